// Round 6
// baseline (197.773 us; speedup 1.0000x reference)
//
#include <hip/hip_runtime.h>

#define NEG (-1e9f)
constexpr int NCLS   = 21;
constexpr int NBOX   = 8732;
constexpr int MAXOUT = 5;
constexpr int CAP    = NBOX;          // worst-case candidates per batch
constexpr float IOU_THR  = 0.5f;
constexpr float CONF_THR = 0.5f;

constexpr int TPB             = 128;
constexpr int BOXES_PER_BLOCK = TPB * 4;                                   // 512
constexpr int BPB             = (NBOX + BOXES_PER_BLOCK - 1) / BOXES_PER_BLOCK; // 18
constexpr int TILE_BYTES      = BOXES_PER_BLOCK * 100;                     // 51200
constexpr int TILE_FLOATS     = TILE_BYTES / 4;                            // 12800

using u64 = unsigned long long;
typedef float f4_t __attribute__((ext_vector_type(4)));

// ---------------------------------------------------------------------------
// Fused kernel v6: decode + compaction + last-block-done NMS (zero-fence
// protocol, proven absmax 0.0 R3-R5), with the load path rebuilt around
// global_load_lds.
// R3-R5 post-mortem: register-staged loads are hard-capped at ~5 outstanding
// 16B loads/wave by the VGPR allocator (48/56/64 VGPR across three coaxing
// attempts); Little's law then pins logical BW at ~1.6 TB/s (=~690 B/CU in
// flight / ~110ns L3 latency) -> 70us floor. R5's asm keep-alive made it
// WORSE (91us): batched loads + full vmcnt(0) drains.
// v6: global_load_lds consumes ZERO VGPRs per outstanding load -> a block
// puts its whole 51.2KB tile (50 wave-instrs x 1024B) in flight at once.
// LDS dest constraint (wave-uniform base + lane*16, m104) is satisfied by a
// LINEAR tile copy. 3 resident blocks/CU -> ~150KB/CU in flight (200x R3)
// -> latency hidden, kernel bound by L3/HBM drain (~111.8MB @ ~5TB/s).
// Compute: ds_read_b128 (16B-aligned: tile base align(16), thread offset
// t*400) + per-box arithmetic IDENTICAL to proven kernel (bit-exact).
// Tail block (28 boxes): OOB lanes' global addrs clamped into the valid
// range; their garbage lands in LDS slots of boxes >= NBOX (never read).
// NMS: M<=64 register-resident fast path, M>64 global fallback (verbatim).
// Candidate record: u64 w0=(y1,x1) w1=(y2,x2) w2=(score,oid) w3=(cls,0).
// ---------------------------------------------------------------------------

__device__ __forceinline__ u64 pk2(float a, float b) {
    union { float f[2]; u64 u; } x; x.f[0] = a; x.f[1] = b; return x.u;
}
__device__ __forceinline__ float lo2(u64 u) { union { u64 v; float f[2]; } x; x.v = u; return x.f[0]; }
__device__ __forceinline__ float hi2(u64 u) { union { u64 v; float f[2]; } x; x.v = u; return x.f[1]; }

__device__ __forceinline__ void ast(u64* p, u64 v) {
    __hip_atomic_store(p, v, __ATOMIC_RELAXED, __HIP_MEMORY_SCOPE_AGENT);
}
__device__ __forceinline__ u64 ald(const u64* p) {
    return __hip_atomic_load(p, __ATOMIC_RELAXED, __HIP_MEMORY_SCOPE_AGENT);
}

// fire-and-forget 16B global->LDS copy (per active lane: g + lane*16 -> l + lane*16)
__device__ __forceinline__ void gload_lds16(const void* g, void* l) {
    __builtin_amdgcn_global_load_lds(
        (const __attribute__((address_space(1))) void*)g,
        (__attribute__((address_space(3))) void*)l,
        16, 0, 0);
}

__device__ __forceinline__ void process_box(
        const float* __restrict__ v,   // 25 floats for this box (registers)
        int b, int n, f4_t db,
        u64* __restrict__ cand,
        int* __restrict__ cnt) {
    // decode (identical expression order to reference)
    float cy = (db[2] + db[0]) * 0.5f;
    float cx = (db[3] + db[1]) * 0.5f;
    float h  = db[2] - db[0];
    float w  = db[3] - db[1];
    float ncy = v[0] * h + cy;
    float ncx = v[1] * w + cx;
    float nh  = expf(v[2]) * h;
    float nw  = expf(v[3]) * w;
    float y1 = fminf(fmaxf(ncy - nh * 0.5f, 0.f), 1.f);
    float x1 = fminf(fmaxf(ncx - nw * 0.5f, 0.f), 1.f);
    float y2 = fminf(fmaxf(ncy + nh * 0.5f, 0.f), 1.f);
    float x2 = fminf(fmaxf(ncx + nw * 0.5f, 0.f), 1.f);

    // argmax(probs)==argmax(logits), first index on ties;
    // max prob = 1/sum(exp(x-max)), same accumulation order as reference
    float m = v[4];
    int am = 0;
#pragma unroll
    for (int j = 1; j < NCLS; j++) {
        float x = v[4 + j];
        if (x > m) { m = x; am = j; }
    }
    float sum = 0.f;
#pragma unroll
    for (int j = 0; j < NCLS; j++) sum += expf(v[4 + j] - m);
    float score = 1.0f / sum;

    if (am != 0 && score > CONF_THR) {
        int p = atomicAdd(&cnt[b], 1);   // device-scope RMW (coherent point)
        if (p < CAP) {
            u64* c = cand + ((long long)b * CAP + p) * 4;
            ast(c + 0, pk2(y1, x1));
            ast(c + 1, pk2(y2, x2));
            ast(c + 2, pk2(score, (float)n));
            ast(c + 3, pk2((float)am, 0.f));
        }
    }
}

__global__ __launch_bounds__(TPB) void fused_kernel(
        const float* __restrict__ logits,
        const float4* __restrict__ dbox4,
        u64* __restrict__ cand,
        int* __restrict__ cnt,
        int* __restrict__ done,
        float* __restrict__ out) {
    const int b    = blockIdx.x / BPB;
    const int blk  = blockIdx.x % BPB;
    const int wave = threadIdx.x >> 6;
    const int lane = threadIdx.x & 63;

    __shared__ __align__(16) float tile[TILE_FLOATS];   // 51.2 KB linear tile
    __shared__ int s_last;

    // ---- stage phase: whole tile in flight via global_load_lds ------------
    const int box0   = blk * BOXES_PER_BLOCK;
    const int nboxes = min(BOXES_PER_BLOCK, NBOX - box0);   // 512 or 28
    const int bytes  = nboxes * 100;                        // valid bytes
    const int ninstr = (bytes + 1023) >> 10;                // 1KB per wave-instr

    const char* gbase =
        (const char*)logits + ((long long)b * NBOX + box0) * 100;

    for (int j = wave; j < ninstr; j += 2) {
        int off = j * 1024 + lane * 16;
        off = min(off, bytes - 16);   // tail clamp: garbage -> never-read slots
        gload_lds16(gbase + off, (char*)tile + (j * 1024));
    }
    __syncthreads();   // vmcnt(0)+lgkmcnt(0) drain before s_barrier: tile ready

    // ---- compute phase ----------------------------------------------------
    const int t  = threadIdx.x;
    const int n0 = box0 + t * 4;     // global box index within batch
    if (n0 < NBOX) {
        const f4_t* lt  = (const f4_t*)(tile + t * 100);   // t*400 B, 16B-aligned
        const f4_t* dbp = (const f4_t*)dbox4;

        float v[100];
#pragma unroll
        for (int k = 0; k < 25; k++) {
            f4_t r = lt[k];
            v[4 * k + 0] = r[0]; v[4 * k + 1] = r[1];
            v[4 * k + 2] = r[2]; v[4 * k + 3] = r[3];
        }
        process_box(v + 0,  b, n0 + 0, dbp[n0 + 0], cand, cnt);
        process_box(v + 25, b, n0 + 1, dbp[n0 + 1], cand, cnt);
        process_box(v + 50, b, n0 + 2, dbp[n0 + 2], cand, cnt);
        process_box(v + 75, b, n0 + 3, dbp[n0 + 3], cand, cnt);
    }

    // ---- completion protocol: zero fences (proven R3) ---------------------
    // __syncthreads drains each wave's vmcnt (sc-flagged stores then globally
    // visible) before the relaxed device-scope RMW on done[b].
    __syncthreads();
    if (threadIdx.x == 0)
        s_last = (__hip_atomic_fetch_add(&done[b], 1, __ATOMIC_RELAXED,
                                         __HIP_MEMORY_SCOPE_AGENT) == BPB - 1);
    __syncthreads();
    if (!s_last) return;             // not the last block for this batch
    if (threadIdx.x >= 64) return;   // NMS = exactly one wave

    // ---- NMS phase (verbatim R3, proven) ----------------------------------
    const int M = min((int)__hip_atomic_load(&cnt[b], __ATOMIC_RELAXED,
                                             __HIP_MEMORY_SCOPE_AGENT), CAP);
    const u64* cb = cand + (long long)b * CAP * 4;
    float* o = out + (long long)b * MAXOUT * 6;

    int k = 0;
    if (M <= 64) {
        // register-resident fast path: one candidate per lane, zero memory
        // traffic inside the selection loop.
        float sc = -INFINITY, oid = 3.0e38f;
        float y1 = 0.f, x1 = 0.f, y2 = 0.f, x2 = 0.f, cls = 0.f;
        if (lane < M) {
            const u64* c = cb + (long long)lane * 4;
            u64 w0 = ald(c + 0), w1 = ald(c + 1), w2 = ald(c + 2), w3 = ald(c + 3);
            y1 = lo2(w0); x1 = hi2(w0);
            y2 = lo2(w1); x2 = hi2(w1);
            sc = lo2(w2); oid = hi2(w2);
            cls = lo2(w3);
        }
        for (; k < MAXOUT; k++) {
            float bv = sc, boid = oid;
            int bi = (lane < M) ? lane : -1;
            for (int mm = 32; mm >= 1; mm >>= 1) {
                float v2 = __shfl_xor(bv,   mm, 64);
                float o2 = __shfl_xor(boid, mm, 64);
                int   i2 = __shfl_xor(bi,   mm, 64);
                if (v2 > bv || (v2 == bv && o2 < boid)) { bv = v2; boid = o2; bi = i2; }
            }
            if (bi < 0 || !(bv > CONF_THR)) break;   // this & later slots -> zeros

            float sy1 = __shfl(y1, bi, 64), sx1 = __shfl(x1, bi, 64);
            float sy2 = __shfl(y2, bi, 64), sx2 = __shfl(x2, bi, 64);
            float scl = __shfl(cls, bi, 64);
            if (lane == 0) {
                o[k * 6 + 0] = sy1; o[k * 6 + 1] = sx1;
                o[k * 6 + 2] = sy2; o[k * 6 + 3] = sx2;
                o[k * 6 + 4] = scl; o[k * 6 + 5] = bv;
            }
            // in-register suppression (selected lane suppresses itself, IoU=1)
            float a1 = (sy2 - sy1) * (sx2 - sx1);
            float tly = fmaxf(sy1, y1);
            float tlx = fmaxf(sx1, x1);
            float bry = fminf(sy2, y2);
            float brx = fminf(sx2, x2);
            float wh0 = fmaxf(bry - tly, 0.f);
            float wh1 = fmaxf(brx - tlx, 0.f);
            float inter = wh0 * wh1;
            float a2 = (y2 - y1) * (x2 - x1);
            float iou = inter / (a1 + a2 - inter + 1e-12f);
            if (lane < M && iou > IOU_THR) sc = NEG;
        }
    } else {
        // general path (never taken for this input; worst-case correctness)
        for (; k < MAXOUT; k++) {
            float bv = -INFINITY, boid = 3.0e38f;
            int bi = -1;
            for (int i = lane; i < M; i += 64) {
                u64 w2 = ald(cb + (long long)i * 4 + 2);
                float v = lo2(w2), od = hi2(w2);
                if (v > bv || (v == bv && od < boid)) { bv = v; boid = od; bi = i; }
            }
            for (int mm = 32; mm >= 1; mm >>= 1) {
                float v2 = __shfl_xor(bv,   mm, 64);
                float o2 = __shfl_xor(boid, mm, 64);
                int   i2 = __shfl_xor(bi,   mm, 64);
                if (v2 > bv || (v2 == bv && o2 < boid)) { bv = v2; boid = o2; bi = i2; }
            }
            if (bi < 0 || !(bv > CONF_THR)) break;

            u64 sw0 = ald(cb + (long long)bi * 4 + 0);
            u64 sw1 = ald(cb + (long long)bi * 4 + 1);
            float sy1 = lo2(sw0), sx1 = hi2(sw0), sy2 = lo2(sw1), sx2 = hi2(sw1);
            if (lane == 0) {
                u64 sw3 = ald(cb + (long long)bi * 4 + 3);
                o[k * 6 + 0] = sy1; o[k * 6 + 1] = sx1;
                o[k * 6 + 2] = sy2; o[k * 6 + 3] = sx2;
                o[k * 6 + 4] = lo2(sw3); o[k * 6 + 5] = bv;
            }
            float a1 = (sy2 - sy1) * (sx2 - sx1);
            for (int i = lane; i < M; i += 64) {
                u64 w0 = ald(cb + (long long)i * 4 + 0);
                u64 w1 = ald(cb + (long long)i * 4 + 1);
                float cy1 = lo2(w0), cx1 = hi2(w0), cy2 = lo2(w1), cx2 = hi2(w1);
                float tly = fmaxf(sy1, cy1);
                float tlx = fmaxf(sx1, cx1);
                float bry = fminf(sy2, cy2);
                float brx = fminf(sx2, cx2);
                float wh0 = fmaxf(bry - tly, 0.f);
                float wh1 = fmaxf(brx - tlx, 0.f);
                float inter = wh0 * wh1;
                float a2 = (cy2 - cy1) * (cx2 - cx1);
                float iou = inter / (a1 + a2 - inter + 1e-12f);
                if (iou > IOU_THR) {
                    u64 w2 = ald(cb + (long long)i * 4 + 2);   // owner lane only
                    ast((u64*)(cb + (long long)i * 4 + 2), pk2(NEG, hi2(w2)));
                }
            }
        }
    }
    for (int j = k * 6 + lane; j < MAXOUT * 6; j += 64) o[j] = 0.f;
}

extern "C" void kernel_launch(void* const* d_in, const int* in_sizes, int n_in,
                              void* d_out, int out_size, void* d_ws, size_t ws_size,
                              hipStream_t stream) {
    const float* logits = (const float*)d_in[0];
    const float4* dbox4 = (const float4*)d_in[1];
    float* out          = (float*)d_out;

    const int N = in_sizes[1] / 4;            // 8732
    const int B = in_sizes[0] / (N * 25);     // 128

    // ws layout: [cnt: B ints][done: B ints][pad to 16B][cand: B*CAP*4 u64]
    int* cnt  = (int*)d_ws;
    int* done = cnt + B;
    u64* cand = (u64*)((char*)d_ws +
        ((2 * (size_t)B * sizeof(int) + 15) & ~(size_t)15));

    hipMemsetAsync(d_ws, 0, 2 * (size_t)B * sizeof(int), stream);
    fused_kernel<<<B * BPB, TPB, 0, stream>>>(logits, dbox4, cand, cnt, done, out);
}

// Round 7
// 187.894 us; speedup vs baseline: 1.0526x; 1.0526x over previous
//
#include <hip/hip_runtime.h>

#define NEG (-1e9f)
constexpr int NCLS   = 21;
constexpr int NBOX   = 8732;
constexpr int MAXOUT = 5;
constexpr int CAP    = NBOX;          // worst-case candidates per batch
constexpr float IOU_THR  = 0.5f;
constexpr float CONF_THR = 0.5f;

constexpr int TPB             = 256;
constexpr int BOXES_PER_BLOCK = TPB * 2;                                   // 512
constexpr int BPB             = (NBOX + BOXES_PER_BLOCK - 1) / BOXES_PER_BLOCK; // 18

using u64 = unsigned long long;
typedef float f2_t __attribute__((ext_vector_type(2)));
typedef float f4_t __attribute__((ext_vector_type(4)));

// ---------------------------------------------------------------------------
// Fused kernel v7: decode + compaction + last-block-done NMS (zero-fence
// protocol, proven absmax 0.0 R3-R6), rebuilt around WAVE COUNT.
// R6 post-mortem (decisive null): full-tile fire-and-forget global_load_lds
// (~150KB/CU in flight, 200x R3) left BW unchanged -> per-wave in-flight
// depth is NOT the limiter. Refit of R0-R6: aggregate BW ~ resident waves x
// ~0.8-1.8 GB/s/wave (per-wave outstanding-line cap); m13's 6.3TB/s copy =
// 32 waves/CU x ~0.8. Old structure (4 boxes/thread) hard-capped total
// waves at 4366 (17/CU). v7: 2 boxes/thread, 256-thr blocks -> 8733 waves
// (36/CU available, saturates the 32 wave slots). float2 loads: 200B/thread
// = 25 x 8B, 8B-aligned (NBOX even -> box pairs never split a float2).
// Loads grouped 13+12 per box -> ~30 floats live, VGPR <= 64 via
// __launch_bounds__(256,8) -> 8 waves/SIMD legal.
// Protocol: relaxed agent-scope atomics, __syncthreads drains vmcnt before
// the done[b] RMW (proven). NMS: M<=64 register-resident fast path, M>64
// global fallback (verbatim). Per-box arithmetic IDENTICAL (bit-exact,
// absmax 0.0 R0-R6).
// Candidate record: u64 w0=(y1,x1) w1=(y2,x2) w2=(score,oid) w3=(cls,0).
// ---------------------------------------------------------------------------

__device__ __forceinline__ u64 pk2(float a, float b) {
    union { float f[2]; u64 u; } x; x.f[0] = a; x.f[1] = b; return x.u;
}
__device__ __forceinline__ float lo2(u64 u) { union { u64 v; float f[2]; } x; x.v = u; return x.f[0]; }
__device__ __forceinline__ float hi2(u64 u) { union { u64 v; float f[2]; } x; x.v = u; return x.f[1]; }

__device__ __forceinline__ void ast(u64* p, u64 v) {
    __hip_atomic_store(p, v, __ATOMIC_RELAXED, __HIP_MEMORY_SCOPE_AGENT);
}
__device__ __forceinline__ u64 ald(const u64* p) {
    return __hip_atomic_load(p, __ATOMIC_RELAXED, __HIP_MEMORY_SCOPE_AGENT);
}

__device__ __forceinline__ void process_box(
        const float* __restrict__ v,   // 25 floats for this box (registers)
        int b, int n, f4_t db,
        u64* __restrict__ cand,
        int* __restrict__ cnt) {
    // decode (identical expression order to reference)
    float cy = (db[2] + db[0]) * 0.5f;
    float cx = (db[3] + db[1]) * 0.5f;
    float h  = db[2] - db[0];
    float w  = db[3] - db[1];
    float ncy = v[0] * h + cy;
    float ncx = v[1] * w + cx;
    float nh  = expf(v[2]) * h;
    float nw  = expf(v[3]) * w;
    float y1 = fminf(fmaxf(ncy - nh * 0.5f, 0.f), 1.f);
    float x1 = fminf(fmaxf(ncx - nw * 0.5f, 0.f), 1.f);
    float y2 = fminf(fmaxf(ncy + nh * 0.5f, 0.f), 1.f);
    float x2 = fminf(fmaxf(ncx + nw * 0.5f, 0.f), 1.f);

    // argmax(probs)==argmax(logits), first index on ties;
    // max prob = 1/sum(exp(x-max)), same accumulation order as reference
    float m = v[4];
    int am = 0;
#pragma unroll
    for (int j = 1; j < NCLS; j++) {
        float x = v[4 + j];
        if (x > m) { m = x; am = j; }
    }
    float sum = 0.f;
#pragma unroll
    for (int j = 0; j < NCLS; j++) sum += expf(v[4 + j] - m);
    float score = 1.0f / sum;

    if (am != 0 && score > CONF_THR) {
        int p = atomicAdd(&cnt[b], 1);   // device-scope RMW (coherent point)
        if (p < CAP) {
            u64* c = cand + ((long long)b * CAP + p) * 4;
            ast(c + 0, pk2(y1, x1));
            ast(c + 1, pk2(y2, x2));
            ast(c + 2, pk2(score, (float)n));
            ast(c + 3, pk2((float)am, 0.f));
        }
    }
}

__global__ __launch_bounds__(TPB, 8) void fused_kernel(
        const float* __restrict__ logits,
        const float4* __restrict__ dbox4,
        u64* __restrict__ cand,
        int* __restrict__ cnt,
        int* __restrict__ done,
        float* __restrict__ out) {
    const int b   = blockIdx.x / BPB;
    const int blk = blockIdx.x % BPB;
    const int t   = threadIdx.x;
    const int n0  = blk * BOXES_PER_BLOCK + t * 2;   // box idx within batch

    __shared__ int s_last;    // ONLY LDS in the kernel (4 bytes)

    // ---- decode phase: 2 boxes per thread, float2 loads -------------------
    if (n0 < NBOX) {
        // pair bytes [200t, 200t+200) of this batch-tile: 25 x float2, 8B-aligned
        const f2_t* f2  = (const f2_t*)(logits + ((long long)b * NBOX + n0) * 25);
        const f4_t* dbp = (const f4_t*)dbox4;

        float v[25];

        // box n0: floats [0..25) = f2[0..12].x/y + f2[12].x
        f2_t r[13];
#pragma unroll
        for (int k = 0; k < 13; k++) r[k] = f2[k];
#pragma unroll
        for (int k = 0; k < 12; k++) { v[2 * k] = r[k][0]; v[2 * k + 1] = r[k][1]; }
        v[24] = r[12][0];
        float carry = r[12][1];          // float 25 = box n0+1's v[0]
        process_box(v, b, n0, dbp[n0], cand, cnt);

        // box n0+1: floats [25..50) = carry + f2[13..24]
        f2_t s[12];
#pragma unroll
        for (int k = 0; k < 12; k++) s[k] = f2[13 + k];
        v[0] = carry;
#pragma unroll
        for (int k = 0; k < 12; k++) { v[1 + 2 * k] = s[k][0]; v[2 + 2 * k] = s[k][1]; }
        process_box(v, b, n0 + 1, dbp[n0 + 1], cand, cnt);
    }

    // ---- completion protocol: zero fences (proven R3) ---------------------
    // __syncthreads drains each wave's vmcnt (sc-flagged stores then globally
    // visible) before the relaxed device-scope RMW on done[b].
    __syncthreads();
    if (threadIdx.x == 0)
        s_last = (__hip_atomic_fetch_add(&done[b], 1, __ATOMIC_RELAXED,
                                         __HIP_MEMORY_SCOPE_AGENT) == BPB - 1);
    __syncthreads();
    if (!s_last) return;             // not the last block for this batch
    if (threadIdx.x >= 64) return;   // NMS = exactly one wave

    // ---- NMS phase (verbatim R3, proven) ----------------------------------
    const int lane = threadIdx.x;
    const int M = min((int)__hip_atomic_load(&cnt[b], __ATOMIC_RELAXED,
                                             __HIP_MEMORY_SCOPE_AGENT), CAP);
    const u64* cb = cand + (long long)b * CAP * 4;
    float* o = out + (long long)b * MAXOUT * 6;

    int k = 0;
    if (M <= 64) {
        // register-resident fast path: one candidate per lane, zero memory
        // traffic inside the selection loop.
        float sc = -INFINITY, oid = 3.0e38f;
        float y1 = 0.f, x1 = 0.f, y2 = 0.f, x2 = 0.f, cls = 0.f;
        if (lane < M) {
            const u64* c = cb + (long long)lane * 4;
            u64 w0 = ald(c + 0), w1 = ald(c + 1), w2 = ald(c + 2), w3 = ald(c + 3);
            y1 = lo2(w0); x1 = hi2(w0);
            y2 = lo2(w1); x2 = hi2(w1);
            sc = lo2(w2); oid = hi2(w2);
            cls = lo2(w3);
        }
        for (; k < MAXOUT; k++) {
            float bv = sc, boid = oid;
            int bi = (lane < M) ? lane : -1;
            for (int mm = 32; mm >= 1; mm >>= 1) {
                float v2 = __shfl_xor(bv,   mm, 64);
                float o2 = __shfl_xor(boid, mm, 64);
                int   i2 = __shfl_xor(bi,   mm, 64);
                if (v2 > bv || (v2 == bv && o2 < boid)) { bv = v2; boid = o2; bi = i2; }
            }
            if (bi < 0 || !(bv > CONF_THR)) break;   // this & later slots -> zeros

            float sy1 = __shfl(y1, bi, 64), sx1 = __shfl(x1, bi, 64);
            float sy2 = __shfl(y2, bi, 64), sx2 = __shfl(x2, bi, 64);
            float scl = __shfl(cls, bi, 64);
            if (lane == 0) {
                o[k * 6 + 0] = sy1; o[k * 6 + 1] = sx1;
                o[k * 6 + 2] = sy2; o[k * 6 + 3] = sx2;
                o[k * 6 + 4] = scl; o[k * 6 + 5] = bv;
            }
            // in-register suppression (selected lane suppresses itself, IoU=1)
            float a1 = (sy2 - sy1) * (sx2 - sx1);
            float tly = fmaxf(sy1, y1);
            float tlx = fmaxf(sx1, x1);
            float bry = fminf(sy2, y2);
            float brx = fminf(sx2, x2);
            float wh0 = fmaxf(bry - tly, 0.f);
            float wh1 = fmaxf(brx - tlx, 0.f);
            float inter = wh0 * wh1;
            float a2 = (y2 - y1) * (x2 - x1);
            float iou = inter / (a1 + a2 - inter + 1e-12f);
            if (lane < M && iou > IOU_THR) sc = NEG;
        }
    } else {
        // general path (never taken for this input; worst-case correctness)
        for (; k < MAXOUT; k++) {
            float bv = -INFINITY, boid = 3.0e38f;
            int bi = -1;
            for (int i = lane; i < M; i += 64) {
                u64 w2 = ald(cb + (long long)i * 4 + 2);
                float v = lo2(w2), od = hi2(w2);
                if (v > bv || (v == bv && od < boid)) { bv = v; boid = od; bi = i; }
            }
            for (int mm = 32; mm >= 1; mm >>= 1) {
                float v2 = __shfl_xor(bv,   mm, 64);
                float o2 = __shfl_xor(boid, mm, 64);
                int   i2 = __shfl_xor(bi,   mm, 64);
                if (v2 > bv || (v2 == bv && o2 < boid)) { bv = v2; boid = o2; bi = i2; }
            }
            if (bi < 0 || !(bv > CONF_THR)) break;

            u64 sw0 = ald(cb + (long long)bi * 4 + 0);
            u64 sw1 = ald(cb + (long long)bi * 4 + 1);
            float sy1 = lo2(sw0), sx1 = hi2(sw0), sy2 = lo2(sw1), sx2 = hi2(sw1);
            if (lane == 0) {
                u64 sw3 = ald(cb + (long long)bi * 4 + 3);
                o[k * 6 + 0] = sy1; o[k * 6 + 1] = sx1;
                o[k * 6 + 2] = sy2; o[k * 6 + 3] = sx2;
                o[k * 6 + 4] = lo2(sw3); o[k * 6 + 5] = bv;
            }
            float a1 = (sy2 - sy1) * (sx2 - sx1);
            for (int i = lane; i < M; i += 64) {
                u64 w0 = ald(cb + (long long)i * 4 + 0);
                u64 w1 = ald(cb + (long long)i * 4 + 1);
                float cy1 = lo2(w0), cx1 = hi2(w0), cy2 = lo2(w1), cx2 = hi2(w1);
                float tly = fmaxf(sy1, cy1);
                float tlx = fmaxf(sx1, cx1);
                float bry = fminf(sy2, cy2);
                float brx = fminf(sx2, cx2);
                float wh0 = fmaxf(bry - tly, 0.f);
                float wh1 = fmaxf(brx - tlx, 0.f);
                float inter = wh0 * wh1;
                float a2 = (cy2 - cy1) * (cx2 - cx1);
                float iou = inter / (a1 + a2 - inter + 1e-12f);
                if (iou > IOU_THR) {
                    u64 w2 = ald(cb + (long long)i * 4 + 2);   // owner lane only
                    ast((u64*)(cb + (long long)i * 4 + 2), pk2(NEG, hi2(w2)));
                }
            }
        }
    }
    for (int j = k * 6 + lane; j < MAXOUT * 6; j += 64) o[j] = 0.f;
}

extern "C" void kernel_launch(void* const* d_in, const int* in_sizes, int n_in,
                              void* d_out, int out_size, void* d_ws, size_t ws_size,
                              hipStream_t stream) {
    const float* logits = (const float*)d_in[0];
    const float4* dbox4 = (const float4*)d_in[1];
    float* out          = (float*)d_out;

    const int N = in_sizes[1] / 4;            // 8732
    const int B = in_sizes[0] / (N * 25);     // 128

    // ws layout: [cnt: B ints][done: B ints][pad to 16B][cand: B*CAP*4 u64]
    int* cnt  = (int*)d_ws;
    int* done = cnt + B;
    u64* cand = (u64*)((char*)d_ws +
        ((2 * (size_t)B * sizeof(int) + 15) & ~(size_t)15));

    hipMemsetAsync(d_ws, 0, 2 * (size_t)B * sizeof(int), stream);
    fused_kernel<<<B * BPB, TPB, 0, stream>>>(logits, dbox4, cand, cnt, done, out);
}